// Round 4
// baseline (2618.095 us; speedup 1.0000x reference)
//
#include <hip/hip_runtime.h>

#define D 128
#define N_ITEMS 200000
#define N_USERS 100000
#define TI 64    // items per score-kernel tile

#define PADN 200192              // N_ITEMS padded to 256 multiple
#define PADU 100096              // N_USERS padded to 256 multiple
#define NT   (3 * PADN + PADU)   // 700672 concatenated counter slots
#define NBLK (NT / 256)          // 2737 scan blocks
#define RSB0 0
#define RSB1 (PADN / 256)        // 782
#define RSB2 (2 * PADN / 256)
#define RSB3 (3 * PADN / 256)    // 2346

#define INV_SQRT_D 0.088388347648318447f

// ---------------------------------------------------------------------------
// Fused histogram over all 4 relations (2 edges/thread, segmented grid).
// ---------------------------------------------------------------------------
__global__ __launch_bounds__(256) void hist_all_kernel(
    const int* __restrict__ d0, const int* __restrict__ d1,
    const int* __restrict__ d2, const int* __restrict__ du,
    unsigned* __restrict__ counts, int Eii, int Eui, int gh)
{
    int bi = blockIdx.x;
    const int* dp; int E; int base; int b0;
    if (bi < 3 * gh) {
        int r = bi / gh;
        dp = (r == 0) ? d0 : (r == 1 ? d1 : d2);
        E = Eii; base = r * PADN; b0 = r * gh;
    } else {
        dp = du; E = Eui; base = 3 * PADN; b0 = 3 * gh;
    }
    int e = ((bi - b0) * 256 + threadIdx.x) * 2;
    if (e + 2 <= E) {
        int a = dp[e], b = dp[e + 1];
        atomicAdd(&counts[base + a], 1u);
        atomicAdd(&counts[base + b], 1u);
    } else if (e < E) {
        atomicAdd(&counts[base + dp[e]], 1u);
    }
}

// ---------------------------------------------------------------------------
// Scan over the whole concatenated counts array (in-place) -> block sums.
// ---------------------------------------------------------------------------
__global__ __launch_bounds__(256) void scan1_kernel(
    unsigned* __restrict__ data, unsigned* __restrict__ blocksums)
{
    __shared__ unsigned s[256];
    int tid = threadIdx.x;
    int i = blockIdx.x * 256 + tid;
    unsigned v = data[i];
    s[tid] = v; __syncthreads();
    #pragma unroll
    for (int off = 1; off < 256; off <<= 1) {
        unsigned t = (tid >= off) ? s[tid - off] : 0u;
        __syncthreads();
        s[tid] += t;
        __syncthreads();
    }
    data[i] = s[tid] - v;                        // exclusive within block
    if (tid == 255) blocksums[blockIdx.x] = s[255];
}

// exclusive scan of up to 4096 block sums (4 per thread)
__global__ __launch_bounds__(1024) void scan2_kernel(
    unsigned* __restrict__ bs, int nb)
{
    __shared__ unsigned s[1024];
    int tid = threadIdx.x;
    int base = tid * 4;
    unsigned v[4]; unsigned tot = 0;
    #pragma unroll
    for (int t = 0; t < 4; ++t) {
        v[t] = (base + t < nb) ? bs[base + t] : 0u;
        tot += v[t];
    }
    s[tid] = tot; __syncthreads();
    #pragma unroll
    for (int off = 1; off < 1024; off <<= 1) {
        unsigned t = (tid >= off) ? s[tid - off] : 0u;
        __syncthreads();
        s[tid] += t;
        __syncthreads();
    }
    unsigned run = s[tid] - tot;                 // exclusive across threads
    #pragma unroll
    for (int t = 0; t < 4; ++t) {
        unsigned old = v[t];
        if (base + t < nb) bs[base + t] = run;
        run += old;
    }
}

// finalize: rebase per relation, write offsets (in place) + cursor copy
__global__ __launch_bounds__(256) void scan3_kernel(
    unsigned* __restrict__ offs, unsigned* __restrict__ cursor,
    const unsigned* __restrict__ bs)
{
    int i = blockIdx.x * 256 + threadIdx.x;
    int rel = (i < 3 * PADN) ? (i / PADN) : 3;
    int rsb = (rel == 0) ? RSB0 : (rel == 1 ? RSB1 : (rel == 2 ? RSB2 : RSB3));
    unsigned o = offs[i] + bs[blockIdx.x] - bs[rsb];
    offs[i] = o;
    cursor[i] = o;
}

// ---------------------------------------------------------------------------
// Scatter: 2 edges/thread, merged loads.
// ---------------------------------------------------------------------------
__global__ __launch_bounds__(256) void scatter_kernel(
    const int* __restrict__ src, const int* __restrict__ dst,
    const float* __restrict__ val, unsigned* __restrict__ cursor,
    int2* __restrict__ pairs, int E)
{
    int e = (blockIdx.x * 256 + threadIdx.x) * 2;
    if (e + 2 <= E) {
        int s0 = src[e], s1 = src[e + 1];
        int d0 = dst[e], d1 = dst[e + 1];
        float v0 = val[e], v1 = val[e + 1];
        unsigned p0 = atomicAdd(&cursor[d0], 1u);
        unsigned p1 = atomicAdd(&cursor[d1], 1u);
        pairs[p0] = make_int2(s0, __float_as_int(v0));
        pairs[p1] = make_int2(s1, __float_as_int(v1));
    } else if (e < E) {
        unsigned p = atomicAdd(&cursor[dst[e]], 1u);
        pairs[p] = make_int2(src[e], __float_as_int(val[e]));
    }
}

// ---------------------------------------------------------------------------
// Gather spmm: one 32-lane group per dst row; 4-deep MLP unroll so four
// independent 512B x-row reads are in flight; coalesced float4 store.
// ---------------------------------------------------------------------------
__global__ __launch_bounds__(256, 8) void gather_spmm_kernel(
    const unsigned* __restrict__ offsets, const int2* __restrict__ pairs,
    const float4* __restrict__ x4, float4* __restrict__ out4, int nrows)
{
    int row = blockIdx.x * 8 + (threadIdx.x >> 5);
    if (row >= nrows) return;
    int lane = threadIdx.x & 31;
    unsigned j = offsets[row], end = offsets[row + 1];
    float4 acc = make_float4(0.f, 0.f, 0.f, 0.f);
    for (; j + 4 <= end; j += 4) {
        int2 p0 = pairs[j];
        int2 p1 = pairs[j + 1];
        int2 p2 = pairs[j + 2];
        int2 p3 = pairs[j + 3];
        float4 a = x4[(size_t)p0.x * 32 + lane];
        float4 b = x4[(size_t)p1.x * 32 + lane];
        float4 c = x4[(size_t)p2.x * 32 + lane];
        float4 d = x4[(size_t)p3.x * 32 + lane];
        float v0 = __int_as_float(p0.y), v1 = __int_as_float(p1.y);
        float v2 = __int_as_float(p2.y), v3 = __int_as_float(p3.y);
        acc.x = fmaf(v0, a.x, acc.x); acc.y = fmaf(v0, a.y, acc.y);
        acc.z = fmaf(v0, a.z, acc.z); acc.w = fmaf(v0, a.w, acc.w);
        acc.x = fmaf(v1, b.x, acc.x); acc.y = fmaf(v1, b.y, acc.y);
        acc.z = fmaf(v1, b.z, acc.z); acc.w = fmaf(v1, b.w, acc.w);
        acc.x = fmaf(v2, c.x, acc.x); acc.y = fmaf(v2, c.y, acc.y);
        acc.z = fmaf(v2, c.z, acc.z); acc.w = fmaf(v2, c.w, acc.w);
        acc.x = fmaf(v3, d.x, acc.x); acc.y = fmaf(v3, d.y, acc.y);
        acc.z = fmaf(v3, d.z, acc.z); acc.w = fmaf(v3, d.w, acc.w);
    }
    if (j + 2 <= end) {
        int2 p0 = pairs[j];
        int2 p1 = pairs[j + 1];
        float4 a = x4[(size_t)p0.x * 32 + lane];
        float4 b = x4[(size_t)p1.x * 32 + lane];
        float v0 = __int_as_float(p0.y), v1 = __int_as_float(p1.y);
        acc.x = fmaf(v0, a.x, acc.x); acc.y = fmaf(v0, a.y, acc.y);
        acc.z = fmaf(v0, a.z, acc.z); acc.w = fmaf(v0, a.w, acc.w);
        acc.x = fmaf(v1, b.x, acc.x); acc.y = fmaf(v1, b.y, acc.y);
        acc.z = fmaf(v1, b.z, acc.z); acc.w = fmaf(v1, b.w, acc.w);
        j += 2;
    }
    if (j < end) {
        int2 p0 = pairs[j];
        float4 a = x4[(size_t)p0.x * 32 + lane];
        float v0 = __int_as_float(p0.y);
        acc.x = fmaf(v0, a.x, acc.x); acc.y = fmaf(v0, a.y, acc.y);
        acc.z = fmaf(v0, a.z, acc.z); acc.w = fmaf(v0, a.w, acc.w);
    }
    out4[(size_t)row * 32 + lane] = acc;
}

// ---------------------------------------------------------------------------
// Fused gated-attention score + softmax + weighted-combine kernel, v4.
//   v3 + XOR-swizzled Tt placement: staging store banks go 4-way -> 2-way
//   (free). Swizzle: item' = item ^ (((k>>5)&3)<<1); applied identically on
//   store and read, bijective within each 64-item row.
// ---------------------------------------------------------------------------
__global__ __launch_bounds__(256, 4) void score_combine_kernel(
    const float4* __restrict__ x4,
    float4* __restrict__ nb0,                       // in: nb_in, out: neighbor
    const float4* __restrict__ nb1, const float4* __restrict__ nb2,
    const float* __restrict__ I0, const float* __restrict__ I1,
    const float* __restrict__ I2)
{
    __shared__ float Tt[D * 65];        // [k][item^swz], stride 65: 33280 B
    __shared__ float Sred[3 * 4 * 64];  // per-rel per-wave partial sums
    __shared__ float Wl[TI * 3];        // softmax weights

    const int tid  = threadIdx.x;
    const int lane = tid & 63;
    const int wv   = __builtin_amdgcn_readfirstlane(tid >> 6);  // wave id 0..3
    const int ilo  = tid >> 5;          // 0..7
    const int dd4  = tid & 31;          // k-quad within row
    const int itemBase = blockIdx.x * TI;
    const int sswz = (dd4 >> 3) & 3;    // = (k>>5) for k in this thread's quad

    // cache the x tile in registers (8 float4 per thread, reused for 3 rels)
    float4 xr[8];
    #pragma unroll
    for (int it = 0; it < 8; ++it) {
        int il = it * 8 + ilo;
        xr[it] = x4[(size_t)(itemBase + il) * 32 + dd4];
    }

    const float4* nbs[3] = {(const float4*)nb0, nb1, nb2};
    const float*  Is[3]  = {I0, I1, I2};

    for (int rel = 0; rel < 3; ++rel) {
        __syncthreads();    // waves done reading Tt from previous rel
        // ---- stage Tt = x * nb, transposed [k][item^swz] ----
        const float4* nbp = nbs[rel];
        #pragma unroll
        for (int it = 0; it < 8; ++it) {
            int il = it * 8 + ilo;
            float4 b = nbp[(size_t)(itemBase + il) * 32 + dd4];
            float4 a = xr[it];
            int ilx = il ^ (sswz << 1);
            int base = (dd4 * 4) * 65 + ilx;
            Tt[base]       = a.x * b.x;
            Tt[base + 65]  = a.y * b.y;
            Tt[base + 130] = a.z * b.z;
            Tt[base + 195] = a.w * b.w;
        }
        __syncthreads();

        // ---- h(item=lane, j in wave's quarter) = sum_k t[k]*I[k][j] ----
        const float4* Iw4 = (const float4*)Is[rel] + wv * 8;   // wave-uniform
        float4 acc[8];
        #pragma unroll
        for (int c = 0; c < 8; ++c) acc[c] = make_float4(0.f, 0.f, 0.f, 0.f);

        #pragma unroll 2
        for (int k = 0; k < D; ++k) {
            float tv = Tt[k * 65 + (lane ^ (((k >> 5) & 3) << 1))];
            #pragma unroll
            for (int c = 0; c < 8; ++c) {
                float4 iv = Iw4[k * 32 + c];     // s_load: wave-uniform addr
                acc[c].x = fmaf(tv, iv.x, acc[c].x);
                acc[c].y = fmaf(tv, iv.y, acc[c].y);
                acc[c].z = fmaf(tv, iv.z, acc[c].z);
                acc[c].w = fmaf(tv, iv.w, acc[c].w);
            }
        }

        // ---- leaky + partial row-sum over this wave's 32 columns ----
        float s = 0.f;
        #pragma unroll
        for (int c = 0; c < 8; ++c) {
            s += fmaxf(acc[c].x, 0.2f * acc[c].x);
            s += fmaxf(acc[c].y, 0.2f * acc[c].y);
            s += fmaxf(acc[c].z, 0.2f * acc[c].z);
            s += fmaxf(acc[c].w, 0.2f * acc[c].w);
        }
        Sred[rel * 256 + wv * 64 + lane] = s;
    }
    __syncthreads();

    // ---- reduce wave partials, softmax over relations -> LDS weights ----
    if (tid < TI) {
        float sr[3];
        #pragma unroll
        for (int r = 0; r < 3; ++r)
            sr[r] = (Sred[r * 256 + tid] + Sred[r * 256 + 64 + tid] +
                     Sred[r * 256 + 128 + tid] + Sred[r * 256 + 192 + tid])
                    * INV_SQRT_D;
        float m = fmaxf(sr[0], fmaxf(sr[1], sr[2]));
        float e0 = expf(sr[0] - m), e1 = expf(sr[1] - m), e2 = expf(sr[2] - m);
        float inv = 1.f / (e0 + e1 + e2);
        Wl[tid * 3 + 0] = e0 * inv;
        Wl[tid * 3 + 1] = e1 * inv;
        Wl[tid * 3 + 2] = e2 * inv;
    }
    __syncthreads();

    // ---- fused weighted combine, in place over nb0 ----
    #pragma unroll
    for (int it = 0; it < 8; ++it) {
        int il = it * 8 + ilo;
        size_t g = (size_t)(itemBase + il) * 32 + dd4;
        float w0 = Wl[il * 3 + 0], w1 = Wl[il * 3 + 1], w2 = Wl[il * 3 + 2];
        float4 a = nb0[g], b = nb1[g], c = nb2[g];
        float4 r;
        r.x = fmaf(w0, a.x, fmaf(w1, b.x, w2 * c.x));
        r.y = fmaf(w0, a.y, fmaf(w1, b.y, w2 * c.y));
        r.z = fmaf(w0, a.z, fmaf(w1, b.z, w2 * c.z));
        r.w = fmaf(w0, a.w, fmaf(w1, b.w, w2 * c.w));
        nb0[g] = r;
    }
}

extern "C" void kernel_launch(void* const* d_in, const int* in_sizes, int n_in,
                              void* d_out, int out_size, void* d_ws, size_t ws_size,
                              hipStream_t stream) {
    const float* x       = (const float*)d_in[1];
    const int*   src0    = (const int*)d_in[2];
    const int*   dst0    = (const int*)d_in[3];
    const float* val0    = (const float*)d_in[4];
    const int*   src1    = (const int*)d_in[5];
    const int*   dst1    = (const int*)d_in[6];
    const float* val1    = (const float*)d_in[7];
    const int*   src2    = (const int*)d_in[8];
    const int*   dst2    = (const int*)d_in[9];
    const float* val2    = (const float*)d_in[10];
    const int*   src_ui  = (const int*)d_in[11];
    const int*   dst_ui  = (const int*)d_in[12];
    const float* val_ui  = (const float*)d_in[13];
    const float* I0      = (const float*)d_in[14];
    const float* I1      = (const float*)d_in[15];
    const float* I2      = (const float*)d_in[16];

    const int E_ii = in_sizes[2];
    const int E_ui = in_sizes[11];

    float* u_emb = (float*)d_out;                          // [N_USERS*D], written last
    float* nb0   = (float*)d_out + (size_t)N_USERS * D;    // neighbor slot doubles as nb_in

    // workspace layout (~210.5 MB)
    float*    nb1       = (float*)d_ws;                                  // 102.4 MB
    float*    nb2       = nb1 + (size_t)N_ITEMS * D;                     // 102.4 MB
    unsigned* counts    = (unsigned*)(nb2 + (size_t)N_ITEMS * D);        // NT u32 (offsets in place)
    unsigned* cursor    = counts + NT;                                   // NT u32
    unsigned* blocksums = cursor + NT;                                   // 4096 u32
    // pairs scratch: ii pairs in the u_emb output region (dead until gather_ui);
    // ui pairs in the nb2 region (dead after score_combine reads nb2)
    int2*     pairs_ii  = (int2*)d_out;                                  // 25.6 MB <= 51.2 MB
    int2*     pairs_ui  = (int2*)nb2;                                    // 12.8 MB <= 102.4 MB

    const int gh  = (E_ii + 511) / 512;   // hist blocks per ii relation
    const int ghu = (E_ui + 511) / 512;
    const int gsE  = (E_ii + 511) / 512;  // scatter blocks (2 edges/thread)
    const int gsEu = (E_ui + 511) / 512;

    // ---- fused CSR metadata build for all 4 relations ----
    hipMemsetAsync(counts, 0, (size_t)NT * sizeof(unsigned), stream);
    hist_all_kernel<<<3 * gh + ghu, 256, 0, stream>>>(
        dst0, dst1, dst2, dst_ui, counts, E_ii, E_ui, gh);
    scan1_kernel<<<NBLK, 256, 0, stream>>>(counts, blocksums);
    scan2_kernel<<<1, 1024, 0, stream>>>(blocksums, NBLK);
    scan3_kernel<<<NBLK, 256, 0, stream>>>(counts, cursor, blocksums);

    // ---- per-relation scatter + gather (shared pairs_ii buffer) ----
    const int* srcs[3] = {src0, src1, src2};
    const int* dsts[3] = {dst0, dst1, dst2};
    const float* vals[3] = {val0, val1, val2};
    float* outs[3] = {nb0, nb1, nb2};
    for (int r = 0; r < 3; ++r) {
        scatter_kernel<<<gsE, 256, 0, stream>>>(
            srcs[r], dsts[r], vals[r], cursor + r * PADN, pairs_ii, E_ii);
        gather_spmm_kernel<<<(N_ITEMS + 7) / 8, 256, 0, stream>>>(
            counts + r * PADN, pairs_ii, (const float4*)x, (float4*)outs[r],
            N_ITEMS);
    }

    // ---- fused score + softmax + combine (in-place over nb0) ----
    score_combine_kernel<<<N_ITEMS / TI, 256, 0, stream>>>(
        (const float4*)x, (float4*)nb0, (const float4*)nb1, (const float4*)nb2,
        I0, I1, I2);

    // ---- user-item last: pairs in nb2 region (dead), writes u_emb ----
    scatter_kernel<<<gsEu, 256, 0, stream>>>(
        src_ui, dst_ui, val_ui, cursor + 3 * PADN, pairs_ui, E_ui);
    gather_spmm_kernel<<<(N_USERS + 7) / 8, 256, 0, stream>>>(
        counts + 3 * PADN, pairs_ui, (const float4*)x, (float4*)u_emb, N_USERS);
}